// Round 4
// baseline (2112.052 us; speedup 1.0000x reference)
//
#include <hip/hip_runtime.h>

namespace {
constexpr int kB = 16;
constexpr int kN = 8732;
constexpr int kC = 20;
constexpr int kRow = 25;      // 1 + C + 4
constexpr int kKeep = 300;    // NNS_K
constexpr int kTot = 200;     // K_TOTAL
constexpr float kConf = 0.01f;
// fl32(inter/union) > 0.45f  <=>  inter/union > 0.45f + ulp/2 (0.45f mantissa even,
// tie rounds down). kThr = 30198989 * 2^-26 exactly; 26-bit x 24-bit product
// is <= 50 bits -> exact in f64, so the f64 compare is an exact emulation.
constexpr double kThr = 0.45000000298023223876953125;

constexpr int TPB1 = 384;     // 6 waves; 2 blocks/CU co-resident (no dispatch tail)
constexpr int EPT1 = 23;      // 384*23 = 8832 >= 8732
constexpr int NW1 = TPB1 / 64;

constexpr int kFlat = kC * kKeep;  // 6000
constexpr int kChunk = 94;         // ceil(6000/64)
constexpr int kPad = 129;          // 129 % 32 == 1 -> conflict-free chunk writes
}

// (score, idx) strict ordering: higher score wins; ties -> lower index.
__device__ __forceinline__ bool pgt(float as, unsigned ai, float bs, unsigned bi) {
  return (as > bs) || ((as == bs) && (ai < bi));
}

// One block per (b, c) task: iterative-argmax greedy NMS with TOP-2 BATCHING:
// per round select c1 = best survivor, and c2 = 2nd best IF it survives c1
// (exact same greedy semantics; halves the number of rounds).
// __launch_bounds__(384, 3): VGPR cap 170, 12 waves/CU -> 2 blocks/CU ->
// all 320 blocks co-resident.
__global__ __launch_bounds__(TPB1, 3) void nms_kernel(const float* __restrict__ in,
                                                      float* __restrict__ ws_s,
                                                      float* __restrict__ ws_b) {
  const int task = blockIdx.x;
  const int b = task / kC;
  const int c = task - b * kC;
  const int tid = threadIdx.x;
  const int lane = tid & 63;
  const int wid = tid >> 6;

  const float* __restrict__ base = in + (size_t)b * kN * kRow;

  float sc[EPT1], by1[EPT1], bx1[EPT1], by2[EPT1], bx2[EPT1];
  float t1s = -1.0f, t2s = -1.0f;
  unsigned t1i = 0, t2i = 0;
#pragma unroll
  for (int k = 0; k < EPT1; ++k) {
    const int n = tid + k * TPB1;
    if (n < kN) {
      const float* r = base + (size_t)n * kRow;
      const float s = r[1 + c];
      by1[k] = r[21]; bx1[k] = r[22]; by2[k] = r[23]; bx2[k] = r[24];
      sc[k] = (s > kConf) ? s : -1.0f;
    } else {
      by1[k] = bx1[k] = by2[k] = bx2[k] = 0.0f;
      sc[k] = -1.0f;
    }
    // per-thread exact top-2 cascade (k ascending => idx ascending; strict >
    // keeps the earliest element on score ties)
    const float s0 = sc[k];
    const unsigned n0 = (unsigned)(tid + k * TPB1);
    const bool u1 = s0 > t1s;
    const bool u2 = s0 > t2s;
    t2s = u1 ? t1s : (u2 ? s0 : t2s);
    t2i = u1 ? t1i : (u2 ? n0 : t2i);
    t1s = u1 ? s0 : t1s;
    t1i = u1 ? n0 : t1i;
  }

  __shared__ float s_ps[NW1][2];
  __shared__ unsigned s_pn[NW1][2];
  __shared__ float s_box[2][4];
  __shared__ float s_ar[2];
  __shared__ float sel_s_l[kKeep];
  __shared__ unsigned sel_n_l[kKeep];

  int cnt = 0;
  for (;;) {
    if (cnt >= kKeep) break;
    // wave-level top-2 butterfly merge of (t1, t2) pairs
    float a1s = t1s, a2s = t2s;
    unsigned a1i = t1i, a2i = t2i;
#pragma unroll
    for (int off = 32; off; off >>= 1) {
      const float o1s = __shfl_xor(a1s, off);
      const unsigned o1i = __shfl_xor(a1i, off);
      const float o2s = __shfl_xor(a2s, off);
      const unsigned o2i = __shfl_xor(a2i, off);
      const bool cw = pgt(a1s, a1i, o1s, o1i);  // a1 is overall best?
      const float w2s = cw ? a2s : o2s;         // winner's 2nd
      const unsigned w2i = cw ? a2i : o2i;
      const float l1s = cw ? o1s : a1s;         // loser's 1st
      const unsigned l1i = cw ? o1i : a1i;
      const bool d = pgt(w2s, w2i, l1s, l1i);
      a1s = cw ? a1s : o1s;
      a1i = cw ? a1i : o1i;
      a2s = d ? w2s : l1s;
      a2i = d ? w2i : l1i;
    }
    if (lane == 0) {
      s_ps[wid][0] = a1s; s_ps[wid][1] = a2s;
      s_pn[wid][0] = a1i; s_pn[wid][1] = a2i;
    }
    __syncthreads();  // B1: per-wave top-2 visible
    float g1s = s_ps[0][0], g2s = s_ps[0][1];
    unsigned g1i = s_pn[0][0], g2i = s_pn[0][1];
#pragma unroll
    for (int w = 1; w < NW1; ++w) {
      const float o1s = s_ps[w][0], o2s = s_ps[w][1];
      const unsigned o1i = s_pn[w][0], o2i = s_pn[w][1];
      const bool cw = pgt(g1s, g1i, o1s, o1i);
      const float w2s = cw ? g2s : o2s;
      const unsigned w2i = cw ? g2i : o2i;
      const float l1s = cw ? o1s : g1s;
      const unsigned l1i = cw ? o1i : g1i;
      const bool d = pgt(w2s, w2i, l1s, l1i);
      g1s = cw ? g1s : o1s;
      g1i = cw ? g1i : o1i;
      g2s = d ? w2s : l1s;
      g2i = d ? w2i : l1i;
    }
    if (g1s <= 0.0f) break;  // uniform: no candidates remain
    const bool have2 = (g2s > 0.0f) && (cnt + 1 < kKeep);
    // publish c1 box (+ owner zap); publish c2 box (zap deferred until v2 known)
    if (tid == (int)(g1i % (unsigned)TPB1)) {
#pragma unroll
      for (int k = 0; k < EPT1; ++k) {
        if ((unsigned)(tid + k * TPB1) == g1i) {
          s_box[0][0] = by1[k]; s_box[0][1] = bx1[k];
          s_box[0][2] = by2[k]; s_box[0][3] = bx2[k];
          s_ar[0] = __fmul_rn(__fsub_rn(by2[k], by1[k]), __fsub_rn(bx2[k], bx1[k]));
          sc[k] = -1.0f;
        }
      }
    }
    if (have2 && tid == (int)(g2i % (unsigned)TPB1)) {
#pragma unroll
      for (int k = 0; k < EPT1; ++k) {
        if ((unsigned)(tid + k * TPB1) == g2i) {
          s_box[1][0] = by1[k]; s_box[1][1] = bx1[k];
          s_box[1][2] = by2[k]; s_box[1][3] = bx2[k];
          s_ar[1] = __fmul_rn(__fsub_rn(by2[k], by1[k]), __fsub_rn(bx2[k], bx1[k]));
        }
      }
    }
    __syncthreads();  // B2: boxes + c1-zap visible
    const float p1y1 = s_box[0][0], p1x1 = s_box[0][1], p1y2 = s_box[0][2],
                p1x2 = s_box[0][3], p1a = s_ar[0];
    const float p2y1 = s_box[1][0], p2x1 = s_box[1][1], p2y2 = s_box[1][2],
                p2x2 = s_box[1][3], p2a = s_ar[1];
    // v2: does c2 survive c1? (computed redundantly & uniformly by all threads)
    bool v2 = have2;
    {
      const float ty1 = fmaxf(p2y1, p1y1);
      const float tx1 = fmaxf(p2x1, p1x1);
      const float ty2 = fminf(p2y2, p1y2);
      const float tx2 = fminf(p2x2, p1x2);
      const float dy = fmaxf(__fsub_rn(ty2, ty1), 0.0f);
      const float dx = fmaxf(__fsub_rn(tx2, tx1), 0.0f);
      const float inter = __fmul_rn(dy, dx);
      const float uni = __fsub_rn(__fadd_rn(p1a, p2a), inter);
      v2 = v2 && !((double)inter > kThr * (double)uni);
    }
    if (tid == 0) {
      sel_s_l[cnt] = g1s; sel_n_l[cnt] = g1i;
      if (v2) { sel_s_l[cnt + 1] = g2s; sel_n_l[cnt + 1] = g2i; }
    }
    if (v2 && tid == (int)(g2i % (unsigned)TPB1)) {
#pragma unroll
      for (int k = 0; k < EPT1; ++k)
        if ((unsigned)(tid + k * TPB1) == g2i) sc[k] = -1.0f;
    }
    // fused sweep: suppress vs c1 (+c2 if v2), rebuild per-thread top-2
    t1s = -1.0f; t2s = -1.0f; t1i = 0; t2i = 0;
#pragma unroll
    for (int k = 0; k < EPT1; ++k) {
      const float ey1 = by1[k], ex1 = bx1[k], ey2 = by2[k], ex2 = bx2[k];
      const float ea = __fmul_rn(__fsub_rn(ey2, ey1), __fsub_rn(ex2, ex1));
      // vs c1
      float ty1 = fmaxf(ey1, p1y1);
      float tx1 = fmaxf(ex1, p1x1);
      float ty2 = fminf(ey2, p1y2);
      float tx2 = fminf(ex2, p1x2);
      float dy = fmaxf(__fsub_rn(ty2, ty1), 0.0f);
      float dx = fmaxf(__fsub_rn(tx2, tx1), 0.0f);
      float inter = __fmul_rn(dy, dx);
      float uni = __fsub_rn(__fadd_rn(p1a, ea), inter);
      // exact emulation of (uni>0) && fl32(inter/uni) > 0.45f (uni>=0 provable;
      // uni==0 => inter==0 => false, so no guard needed)
      bool kill = ((double)inter > kThr * (double)uni);
      // vs c2 (masked by v2)
      ty1 = fmaxf(ey1, p2y1);
      tx1 = fmaxf(ex1, p2x1);
      ty2 = fminf(ey2, p2y2);
      tx2 = fminf(ex2, p2x2);
      dy = fmaxf(__fsub_rn(ty2, ty1), 0.0f);
      dx = fmaxf(__fsub_rn(tx2, tx1), 0.0f);
      inter = __fmul_rn(dy, dx);
      uni = __fsub_rn(__fadd_rn(p2a, ea), inter);
      kill = kill || (v2 && ((double)inter > kThr * (double)uni));
      const float s0 = kill ? -1.0f : sc[k];
      sc[k] = s0;
      const unsigned n0 = (unsigned)(tid + k * TPB1);
      const bool u1 = s0 > t1s;
      const bool u2 = s0 > t2s;
      t2s = u1 ? t1s : (u2 ? s0 : t2s);
      t2i = u1 ? t1i : (u2 ? n0 : t2i);
      t1s = u1 ? s0 : t1s;
      t1i = u1 ? n0 : t1i;
    }
    cnt += 1 + (v2 ? 1 : 0);
  }
  __syncthreads();  // make sel_s_l / sel_n_l (written by tid 0) visible to all

  // bulk write selected results (boxes re-read from input: bit-identical)
  float* __restrict__ out_s = ws_s + (size_t)task * kKeep;
  float* __restrict__ out_b = ws_b + (size_t)task * kKeep * 4;
  for (int i = tid; i < kKeep; i += TPB1) {
    if (i < cnt) {
      out_s[i] = sel_s_l[i];
      const float* r = base + (size_t)sel_n_l[i] * kRow;
      out_b[i * 4 + 0] = r[21];
      out_b[i * 4 + 1] = r[22];
      out_b[i * 4 + 2] = r[23];
      out_b[i * 4 + 3] = r[24];
    } else {
      out_s[i] = -1.0f;
    }
  }
}

// One wave per batch: stable top-200 (descending score, min flat-index ties),
// mirroring jax.lax.top_k. Incremental per-lane max; on removal only the
// owner lane's chunk is rescanned (all 64 lanes assist).
__global__ __launch_bounds__(64) void topk_kernel(const float* __restrict__ ws_s,
                                                  const float* __restrict__ ws_b,
                                                  float* __restrict__ out) {
  const int b = blockIdx.x;
  const int lane = threadIdx.x;
  const float* __restrict__ ss = ws_s + (size_t)b * kFlat;
  const float* __restrict__ bb = ws_b + (size_t)b * kFlat * 4;
  float* __restrict__ ob = out + (size_t)b * kTot * 6;

  __shared__ float lds[64 * kPad];

  // lane owns flat indices [lane*94, lane*94+94) at LDS slots [lane*129, ...)
  float lmax = -2.0f;
  unsigned lidx = 0;
  for (int i = 0; i < kChunk; ++i) {
    const int f = lane * kChunk + i;
    const float v = (f < kFlat) ? ss[f] : -2.0f;
    const unsigned slot = (unsigned)(lane * kPad + i);
    lds[slot] = v;
    const bool up = v > lmax;
    lmax = up ? v : lmax;
    lidx = up ? slot : lidx;
  }
  for (int i = kChunk; i < kPad; ++i) lds[lane * kPad + i] = -2.0f;
  __syncthreads();

  int r = 0;
  for (; r < kTot; ++r) {
    // butterfly (score, min-slot) reduce; slot order == flat order
    float bs = lmax;
    unsigned bn = lidx;
#pragma unroll
    for (int off = 32; off; off >>= 1) {
      const float os = __shfl_xor(bs, off);
      const unsigned on = __shfl_xor(bn, off);
      const bool take = (os > bs) || ((os == bs) && (on < bn));
      bs = take ? os : bs;
      bn = take ? on : bn;
    }
    if (bs <= 0.0f) break;  // only empty(-1)/pad(-2) remain
    const unsigned gslot = bn;
    const unsigned owner = gslot / kPad;
    const unsigned f = owner * kChunk + (gslot - owner * kPad);

    // box fetch (uniform address; loads overlap the rescan below)
    const float q0 = bb[f * 4 + 0];
    const float q1 = bb[f * 4 + 1];
    const float q2 = bb[f * 4 + 2];
    const float q3 = bb[f * 4 + 3];

    // remove selected, rescan owner chunk (all lanes assist)
    if (lane == 0) lds[gslot] = -2.0f;
    __syncthreads();
    const unsigned baseo = owner * kPad;
    float ns = -2.0f;
    unsigned nn = 0;
#pragma unroll
    for (int j = 0; j < 2; ++j) {
      const unsigned idx = baseo + j * 64 + lane;  // < baseo + 128 <= baseo + kPad-1
      const float v = lds[idx];
      const bool up = v > ns;
      ns = up ? v : ns;
      nn = up ? idx : nn;
    }
#pragma unroll
    for (int off = 32; off; off >>= 1) {
      const float os = __shfl_xor(ns, off);
      const unsigned on = __shfl_xor(nn, off);
      const bool take = (os > ns) || ((os == ns) && (on < nn));
      ns = take ? os : ns;
      nn = take ? on : nn;
    }
    if (lane == (int)owner) { lmax = ns; lidx = nn; }

    if (lane == 0) {
      const unsigned cls = f / kKeep;  // 0..19
      ob[r * 6 + 0] = (float)(cls + 1);
      ob[r * 6 + 1] = bs;
      ob[r * 6 + 2] = fminf(fmaxf(q0, 0.0f), 1.0f);
      ob[r * 6 + 3] = fminf(fmaxf(q1, 0.0f), 1.0f);
      ob[r * 6 + 4] = fminf(fmaxf(q2, 0.0f), 1.0f);
      ob[r * 6 + 5] = fminf(fmaxf(q3, 0.0f), 1.0f);
    }
    __syncthreads();
  }
  // invalid rows: class = 0+1 = 1, score 0, boxes 0
  for (int idx = r * 6 + lane; idx < kTot * 6; idx += 64) {
    ob[idx] = ((idx % 6) == 0) ? 1.0f : 0.0f;
  }
}

extern "C" void kernel_launch(void* const* d_in, const int* in_sizes, int n_in,
                              void* d_out, int out_size, void* d_ws, size_t ws_size,
                              hipStream_t stream) {
  const float* in = (const float*)d_in[0];
  float* out = (float*)d_out;
  float* ws_s = (float*)d_ws;                    // 320*300 floats
  float* ws_b = ws_s + (size_t)kB * kC * kKeep;  // 320*300*4 floats
  nms_kernel<<<dim3(kB * kC), dim3(TPB1), 0, stream>>>(in, ws_s, ws_b);
  topk_kernel<<<dim3(kB), dim3(64), 0, stream>>>(ws_s, ws_b, out);
}

// Round 5
// 1417.194 us; speedup vs baseline: 1.4903x; 1.4903x over previous
//
#include <hip/hip_runtime.h>

typedef unsigned long long u64;
typedef unsigned int u32;
typedef unsigned short u16;

namespace {
constexpr int kB = 16;
constexpr int kN = 8732;
constexpr int kC = 20;
constexpr int kRow = 25;      // 1 + C + 4
constexpr int kKeep = 300;    // NNS_K
constexpr int kTot = 200;     // K_TOTAL
constexpr float kConf = 0.01f;
// fl32(inter/union) > 0.45f  <=>  inter/union > 0.45f + ulp/2 (0.45f mantissa even,
// tie rounds down). kThr = 30198989 * 2^-26 exactly; 26-bit x 24-bit product
// is <= 50 bits -> exact in f64, so the f64 compare is an exact emulation.
constexpr double kThr = 0.45000000298023223876953125;

constexpr int TPB = 256;
constexpr int NBKT = 4096;         // score-bit buckets (bits>>14), range fits 3442
constexpr int kFlat = kC * kKeep;  // 6000
}

// exact emulation of reference: (union>0) && fl32(inter/union) > 0.45f
// (union >= 0 provable by rounding monotonicity; union==0 => inter==0 => false)
__device__ __forceinline__ bool iou_gt(float ay1, float ax1, float ay2, float ax2, float aa,
                                       float by1, float bx1, float by2, float bx2, float ba) {
  const float ty1 = fmaxf(ay1, by1);
  const float tx1 = fmaxf(ax1, bx1);
  const float ty2 = fminf(ay2, by2);
  const float tx2 = fminf(ax2, bx2);
  const float dy = fmaxf(__fsub_rn(ty2, ty1), 0.0f);
  const float dx = fmaxf(__fsub_rn(tx2, tx1), 0.0f);
  const float inter = __fmul_rn(dy, dx);
  const float uni = __fsub_rn(__fadd_rn(aa, ba), inter);
  return ((double)inter > kThr * (double)uni);
}

// bucket by high bits of score: monotone DESC (bucket 0 = highest scores).
// valid for s in (0.01, 1.0]: bits>>14 in [61583, 65024] -> bkt in [0, 3441].
__device__ __forceinline__ int bkt_of(float s) {
  return 65024 - (int)(__float_as_uint(s) >> 14);
}

// packed in-bucket sort key: same bucket => scores share bits[31:14], so
// (low14 desc, 16383-idx desc) == (score desc, idx asc). idx recoverable.
__device__ __forceinline__ u32 key_of(float s, int idx) {
  return ((__float_as_uint(s) & 0x3FFFu) << 14) | (u32)(16383 - idx);
}

// exclusive prefix sum over hist[NBKT]; each of 256 threads owns 16 buckets.
// returns total count. hist[i] becomes the exclusive start of bucket i.
__device__ int excl_scan_hist(u32* hist, u32* wsum, int tid) {
  const int base = tid * 16;
  u32 loc[16];
  u32 s = 0;
#pragma unroll
  for (int i = 0; i < 16; ++i) { loc[i] = hist[base + i]; s += loc[i]; }
  int v = (int)s;
  const int lane = tid & 63;
#pragma unroll
  for (int off = 1; off < 64; off <<= 1) {
    const int u = __shfl_up(v, off);
    if (lane >= off) v += u;
  }
  if (lane == 63) wsum[tid >> 6] = (u32)v;
  __syncthreads();
  u32 woff = 0, total = 0;
#pragma unroll
  for (int w = 0; w < TPB / 64; ++w) {
    const u32 t = wsum[w];
    total += t;
    if (w < (tid >> 6)) woff += t;
  }
  u32 run = woff + (u32)v - s;
#pragma unroll
  for (int i = 0; i < 16; ++i) { hist[base + i] = run; run += loc[i]; }
  __syncthreads();
  return (int)total;
}

// One block per (b,c) task. Phase 1: exact stable sort of candidates by
// (score desc, idx asc) via bucket sort. Phase 2: chunked sequential greedy
// NMS scan over the sorted order (exact reference semantics incl. cnt<300).
__global__ __launch_bounds__(TPB) void nms_kernel(const float* __restrict__ in,
                                                  float* __restrict__ ws_s,
                                                  float* __restrict__ ws_b) {
  const int task = blockIdx.x;
  const int b = task / kC;
  const int c = task - b * kC;
  const int tid = threadIdx.x;
  const float* __restrict__ base_in = in + (size_t)b * kN * kRow;

  __shared__ __align__(16) unsigned char ovl[16384];  // hist | phase-2 scratch
  __shared__ u32 skey[kN];                            // sorted packed keys
  __shared__ float sel_y1[kKeep], sel_x1[kKeep], sel_y2[kKeep], sel_x2[kKeep],
      sel_ar[kKeep];
  __shared__ u32 wsum[TPB / 64];

  u32* hist = (u32*)ovl;
  for (int i = tid; i < NBKT; i += TPB) hist[i] = 0;
  __syncthreads();
  // histogram pass
  for (int k = 0; k < (kN + TPB - 1) / TPB; ++k) {
    const int n = tid + k * TPB;
    if (n < kN) {
      const float s = base_in[(size_t)n * kRow + 1 + c];
      if (s > kConf) atomicAdd(&hist[bkt_of(s)], 1u);
    }
  }
  __syncthreads();
  const int ncand = excl_scan_hist(hist, wsum, tid);
  // scatter pass (atomic order nondeterministic; fixed by in-bucket sort)
  for (int k = 0; k < (kN + TPB - 1) / TPB; ++k) {
    const int n = tid + k * TPB;
    if (n < kN) {
      const float s = base_in[(size_t)n * kRow + 1 + c];
      if (s > kConf) {
        const u32 pos = atomicAdd(&hist[bkt_of(s)], 1u);
        skey[pos] = key_of(s, n);
      }
    }
  }
  __syncthreads();
  // in-bucket insertion sort, descending u32 key (exact total order)
  for (int bkt = tid; bkt < NBKT; bkt += TPB) {
    const int s0 = (bkt == 0) ? 0 : (int)hist[bkt - 1];  // post-scatter = ends
    const int e0 = (int)hist[bkt];
    for (int i = s0 + 1; i < e0; ++i) {
      const u32 kk = skey[i];
      int j = i - 1;
      while (j >= s0 && kk > skey[j]) { skey[j + 1] = skey[j]; --j; }
      skey[j + 1] = kk;
    }
  }
  __syncthreads();  // hist dead -> overlay becomes phase-2 scratch

  u64* rows = (u64*)ovl;               // [256][4] = 8192 B
  float* cy1 = (float*)(ovl + 8192);   // chunk boxes, 1 KB each
  float* cx1 = (float*)(ovl + 9216);
  float* cy2 = (float*)(ovl + 10240);
  float* cx2 = (float*)(ovl + 11264);
  float* car = (float*)(ovl + 12288);
  u32* supp = (u32*)(ovl + 13312);     // 1 KB (total 14336 <= 16384)

  float* __restrict__ out_s = ws_s + (size_t)task * kKeep;
  float* __restrict__ out_b = ws_b + (size_t)task * kKeep * 4;

  int cnt = 0;
  int basec = 0;
  while (cnt < kKeep && basec < ncand) {
    const int rank = basec + tid;
    const bool havec = rank < ncand;
    const int lim = min(TPB, ncand - basec);
    float ey1 = 0, ex1 = 0, ey2 = 0, ex2 = 0, ea = 0;
    int eidx = 0;
    if (havec) {
      eidx = 16383 - (int)(skey[rank] & 0x3FFFu);
      const float* r = base_in + (size_t)eidx * kRow;
      ey1 = r[21]; ex1 = r[22]; ey2 = r[23]; ex2 = r[24];
      ea = __fmul_rn(__fsub_rn(ey2, ey1), __fsub_rn(ex2, ex1));
    }
    cy1[tid] = ey1; cx1[tid] = ex1; cy2[tid] = ey2; cx2[tid] = ex2; car[tid] = ea;
    // test vs already-selected set (LDS broadcast reads)
    bool sup = !havec;
    for (int i = 0; i < cnt; ++i) {
      sup = sup | iou_gt(ey1, ex1, ey2, ex2, ea,
                         sel_y1[i], sel_x1[i], sel_y2[i], sel_x2[i], sel_ar[i]);
    }
    supp[tid] = sup ? 1u : 0u;
    __syncthreads();  // A: chunk boxes + supp visible
    // in-chunk suppression mask row (vs earlier candidates in this chunk)
    u64 r0 = 0, r1 = 0, r2 = 0, r3 = 0;
    const int jl = havec ? tid : 0;
    for (int t = 0; t < jl; ++t) {
      const bool kill = iou_gt(ey1, ex1, ey2, ex2, ea,
                               cy1[t], cx1[t], cy2[t], cx2[t], car[t]);
      const u64 m = kill ? 1ull : 0ull;
      if (t < 64) r0 |= m << t;
      else if (t < 128) r1 |= m << (t - 64);
      else if (t < 192) r2 |= m << (t - 128);
      else r3 |= m << (t - 192);
    }
    rows[tid * 4 + 0] = r0; rows[tid * 4 + 1] = r1;
    rows[tid * 4 + 2] = r2; rows[tid * 4 + 3] = r3;
    __syncthreads();  // B: rows visible
    // serial resolve (all threads redundantly; fully uniform -> no divergence)
    u64 a0 = 0, a1 = 0, a2 = 0, a3 = 0;
    int nc = cnt;
    int myslot = -1;
    for (int t = 0; t < lim; ++t) {
      bool ok = (supp[t] == 0u) && (nc < kKeep);
      if (ok) {
        const u64 hit = (rows[t * 4 + 0] & a0) | (rows[t * 4 + 1] & a1) |
                        (rows[t * 4 + 2] & a2) | (rows[t * 4 + 3] & a3);
        ok = (hit == 0ull);
      }
      if (ok) {
        if (t == tid) myslot = nc;
        if (t < 64) a0 |= 1ull << t;
        else if (t < 128) a1 |= 1ull << (t - 64);
        else if (t < 192) a2 |= 1ull << (t - 128);
        else a3 |= 1ull << (t - 192);
        ++nc;
      }
    }
    if (myslot >= 0) {
      sel_y1[myslot] = ey1; sel_x1[myslot] = ex1;
      sel_y2[myslot] = ey2; sel_x2[myslot] = ex2;
      sel_ar[myslot] = ea;
      out_s[myslot] = base_in[(size_t)eidx * kRow + 1 + c];  // exact score
      out_b[(size_t)myslot * 4 + 0] = ey1;
      out_b[(size_t)myslot * 4 + 1] = ex1;
      out_b[(size_t)myslot * 4 + 2] = ey2;
      out_b[(size_t)myslot * 4 + 3] = ex2;
    }
    cnt = nc;           // uniform across block
    basec += TPB;
    __syncthreads();    // C: sel visible; chunk scratch reusable
  }
  // empty slots
  for (int i = cnt + tid; i < kKeep; i += TPB) out_s[i] = -1.0f;
}

// One block per batch: stable top-200 via the same exact bucket sort
// (descending score, min flat-index ties == jax.lax.top_k stability).
__global__ __launch_bounds__(TPB) void topk_kernel(const float* __restrict__ ws_s,
                                                   const float* __restrict__ ws_b,
                                                   float* __restrict__ out) {
  const int b = blockIdx.x;
  const int tid = threadIdx.x;
  const float* __restrict__ ss = ws_s + (size_t)b * kFlat;
  const float* __restrict__ bb = ws_b + (size_t)b * kFlat * 4;
  float* __restrict__ ob = out + (size_t)b * kTot * 6;

  __shared__ u32 hist[NBKT];
  __shared__ u32 skey[kFlat];
  __shared__ u32 wsum[TPB / 64];

  for (int i = tid; i < NBKT; i += TPB) hist[i] = 0;
  __syncthreads();
  for (int k = 0; k < (kFlat + TPB - 1) / TPB; ++k) {
    const int f = tid + k * TPB;
    if (f < kFlat) {
      const float s = ss[f];
      if (s > 0.0f) atomicAdd(&hist[bkt_of(s)], 1u);
    }
  }
  __syncthreads();
  const int ncand = excl_scan_hist(hist, wsum, tid);
  for (int k = 0; k < (kFlat + TPB - 1) / TPB; ++k) {
    const int f = tid + k * TPB;
    if (f < kFlat) {
      const float s = ss[f];
      if (s > 0.0f) {
        const u32 pos = atomicAdd(&hist[bkt_of(s)], 1u);
        skey[pos] = key_of(s, f);
      }
    }
  }
  __syncthreads();
  for (int bkt = tid; bkt < NBKT; bkt += TPB) {
    const int s0 = (bkt == 0) ? 0 : (int)hist[bkt - 1];
    const int e0 = (int)hist[bkt];
    for (int i = s0 + 1; i < e0; ++i) {
      const u32 kk = skey[i];
      int j = i - 1;
      while (j >= s0 && kk > skey[j]) { skey[j + 1] = skey[j]; --j; }
      skey[j + 1] = kk;
    }
  }
  __syncthreads();
  const int cnt = min(kTot, ncand);
  if (tid < cnt) {
    const int f = 16383 - (int)(skey[tid] & 0x3FFFu);
    ob[tid * 6 + 0] = (float)(f / kKeep + 1);
    ob[tid * 6 + 1] = ss[f];
    ob[tid * 6 + 2] = fminf(fmaxf(bb[(size_t)f * 4 + 0], 0.0f), 1.0f);
    ob[tid * 6 + 3] = fminf(fmaxf(bb[(size_t)f * 4 + 1], 0.0f), 1.0f);
    ob[tid * 6 + 4] = fminf(fmaxf(bb[(size_t)f * 4 + 2], 0.0f), 1.0f);
    ob[tid * 6 + 5] = fminf(fmaxf(bb[(size_t)f * 4 + 3], 0.0f), 1.0f);
  }
  // invalid rows: class = 0+1 = 1, score 0, boxes 0
  for (int r = cnt + tid; r < kTot; r += TPB) {
    ob[r * 6 + 0] = 1.0f;
    ob[r * 6 + 1] = 0.0f;
    ob[r * 6 + 2] = 0.0f;
    ob[r * 6 + 3] = 0.0f;
    ob[r * 6 + 4] = 0.0f;
    ob[r * 6 + 5] = 0.0f;
  }
}

extern "C" void kernel_launch(void* const* d_in, const int* in_sizes, int n_in,
                              void* d_out, int out_size, void* d_ws, size_t ws_size,
                              hipStream_t stream) {
  const float* in = (const float*)d_in[0];
  float* out = (float*)d_out;
  float* ws_s = (float*)d_ws;                    // 320*300 floats
  float* ws_b = ws_s + (size_t)kB * kC * kKeep;  // 320*300*4 floats
  nms_kernel<<<dim3(kB * kC), dim3(TPB), 0, stream>>>(in, ws_s, ws_b);
  topk_kernel<<<dim3(kB), dim3(TPB), 0, stream>>>(ws_s, ws_b, out);
}

// Round 6
// 481.857 us; speedup vs baseline: 4.3832x; 2.9411x over previous
//
#include <hip/hip_runtime.h>

typedef unsigned long long u64;
typedef unsigned int u32;

namespace {
constexpr int kB = 16;
constexpr int kN = 8732;
constexpr int kC = 20;
constexpr int kRow = 25;      // 1 + C + 4
constexpr int kKeep = 300;    // NNS_K
constexpr int kTot = 200;     // K_TOTAL
constexpr float kConf = 0.01f;
// fl32(inter/union) > 0.45f  <=>  inter/union > 0.45f + ulp/2 (0.45f mantissa even,
// tie rounds down). kThr = 30198989 * 2^-26 exactly; 26-bit x 24-bit product
// is <= 50 bits -> exact in f64, so the f64 compare is an exact emulation.
constexpr double kThr = 0.45000000298023223876953125;

constexpr int TPB = 256;
constexpr int NBKT = 4096;         // score-bit buckets (bits>>14), range fits 3442
constexpr int kFlat = kC * kKeep;  // 6000
}

// exact emulation of reference: (union>0) && fl32(inter/union) > 0.45f
// (union >= 0 provable by rounding monotonicity; union==0 => inter==0 => false)
__device__ __forceinline__ bool iou_gt(float ay1, float ax1, float ay2, float ax2, float aa,
                                       float by1, float bx1, float by2, float bx2, float ba) {
  const float ty1 = fmaxf(ay1, by1);
  const float tx1 = fmaxf(ax1, bx1);
  const float ty2 = fminf(ay2, by2);
  const float tx2 = fminf(ax2, bx2);
  const float dy = fmaxf(__fsub_rn(ty2, ty1), 0.0f);
  const float dx = fmaxf(__fsub_rn(tx2, tx1), 0.0f);
  const float inter = __fmul_rn(dy, dx);
  const float uni = __fsub_rn(__fadd_rn(aa, ba), inter);
  return ((double)inter > kThr * (double)uni);
}

// bucket by high bits of score: monotone DESC (bucket 0 = highest scores).
// valid for s in (0.01, 1.0]: bits>>14 in [61583, 65024] -> bkt in [0, 3441].
__device__ __forceinline__ int bkt_of(float s) {
  return 65024 - (int)(__float_as_uint(s) >> 14);
}

// packed in-bucket sort key: same bucket => scores share bits[31:14], so
// (low14 desc, 16383-idx desc) == (score desc, idx asc). idx recoverable.
__device__ __forceinline__ u32 key_of(float s, int idx) {
  return ((__float_as_uint(s) & 0x3FFFu) << 14) | (u32)(16383 - idx);
}

// (score, flat-idx) strict ordering: higher score wins; ties -> lower idx.
__device__ __forceinline__ bool pgt(float as, u32 ai, float bs, u32 bi) {
  return (as > bs) || ((as == bs) && (ai < bi));
}

// exclusive prefix sum over hist[NBKT]; each of 256 threads owns 16 buckets.
// returns total count. hist[i] becomes the exclusive start of bucket i.
__device__ int excl_scan_hist(u32* hist, u32* wsum, int tid) {
  const int base = tid * 16;
  u32 loc[16];
  u32 s = 0;
#pragma unroll
  for (int i = 0; i < 16; ++i) { loc[i] = hist[base + i]; s += loc[i]; }
  int v = (int)s;
  const int lane = tid & 63;
#pragma unroll
  for (int off = 1; off < 64; off <<= 1) {
    const int u = __shfl_up(v, off);
    if (lane >= off) v += u;
  }
  if (lane == 63) wsum[tid >> 6] = (u32)v;
  __syncthreads();
  u32 woff = 0, total = 0;
#pragma unroll
  for (int w = 0; w < TPB / 64; ++w) {
    const u32 t = wsum[w];
    total += t;
    if (w < (tid >> 6)) woff += t;
  }
  u32 run = woff + (u32)v - s;
#pragma unroll
  for (int i = 0; i < 16; ++i) { hist[base + i] = run; run += loc[i]; }
  __syncthreads();
  return (int)total;
}

// One block per (b,c) task. Phase 1: exact stable sort of candidates by
// (score desc, idx asc) via bucket sort. Phase 2: chunked sequential greedy
// NMS scan over the sorted order (exact reference semantics incl. cnt<300).
__global__ __launch_bounds__(TPB) void nms_kernel(const float* __restrict__ in,
                                                  float* __restrict__ ws_s,
                                                  float* __restrict__ ws_b) {
  const int task = blockIdx.x;
  const int b = task / kC;
  const int c = task - b * kC;
  const int tid = threadIdx.x;
  const float* __restrict__ base_in = in + (size_t)b * kN * kRow;

  __shared__ __align__(16) unsigned char ovl[16384];  // hist | phase-2 scratch
  __shared__ u32 skey[kN];                            // sorted packed keys
  __shared__ float sel_y1[kKeep], sel_x1[kKeep], sel_y2[kKeep], sel_x2[kKeep],
      sel_ar[kKeep];
  __shared__ u32 wsum[TPB / 64];

  u32* hist = (u32*)ovl;
  for (int i = tid; i < NBKT; i += TPB) hist[i] = 0;
  __syncthreads();
  // histogram pass
  for (int k = 0; k < (kN + TPB - 1) / TPB; ++k) {
    const int n = tid + k * TPB;
    if (n < kN) {
      const float s = base_in[(size_t)n * kRow + 1 + c];
      if (s > kConf) atomicAdd(&hist[bkt_of(s)], 1u);
    }
  }
  __syncthreads();
  const int ncand = excl_scan_hist(hist, wsum, tid);
  // scatter pass (atomic order nondeterministic; fixed by in-bucket sort)
  for (int k = 0; k < (kN + TPB - 1) / TPB; ++k) {
    const int n = tid + k * TPB;
    if (n < kN) {
      const float s = base_in[(size_t)n * kRow + 1 + c];
      if (s > kConf) {
        const u32 pos = atomicAdd(&hist[bkt_of(s)], 1u);
        skey[pos] = key_of(s, n);
      }
    }
  }
  __syncthreads();
  // in-bucket insertion sort, descending u32 key (exact total order)
  for (int bkt = tid; bkt < NBKT; bkt += TPB) {
    const int s0 = (bkt == 0) ? 0 : (int)hist[bkt - 1];  // post-scatter = ends
    const int e0 = (int)hist[bkt];
    for (int i = s0 + 1; i < e0; ++i) {
      const u32 kk = skey[i];
      int j = i - 1;
      while (j >= s0 && kk > skey[j]) { skey[j + 1] = skey[j]; --j; }
      skey[j + 1] = kk;
    }
  }
  __syncthreads();  // hist dead -> overlay becomes phase-2 scratch

  u64* rows = (u64*)ovl;               // [256][4] = 8192 B
  float* cy1 = (float*)(ovl + 8192);   // chunk boxes, 1 KB each
  float* cx1 = (float*)(ovl + 9216);
  float* cy2 = (float*)(ovl + 10240);
  float* cx2 = (float*)(ovl + 11264);
  float* car = (float*)(ovl + 12288);
  u32* supp = (u32*)(ovl + 13312);     // 1 KB (total 14336 <= 16384)

  float* __restrict__ out_s = ws_s + (size_t)task * kKeep;
  float* __restrict__ out_b = ws_b + (size_t)task * kKeep * 4;

  int cnt = 0;
  int basec = 0;
  while (cnt < kKeep && basec < ncand) {
    const int rank = basec + tid;
    const bool havec = rank < ncand;
    const int lim = min(TPB, ncand - basec);
    float ey1 = 0, ex1 = 0, ey2 = 0, ex2 = 0, ea = 0;
    int eidx = 0;
    if (havec) {
      eidx = 16383 - (int)(skey[rank] & 0x3FFFu);
      const float* r = base_in + (size_t)eidx * kRow;
      ey1 = r[21]; ex1 = r[22]; ey2 = r[23]; ex2 = r[24];
      ea = __fmul_rn(__fsub_rn(ey2, ey1), __fsub_rn(ex2, ex1));
    }
    cy1[tid] = ey1; cx1[tid] = ex1; cy2[tid] = ey2; cx2[tid] = ex2; car[tid] = ea;
    // test vs already-selected set (LDS broadcast reads)
    bool sup = !havec;
    for (int i = 0; i < cnt; ++i) {
      sup = sup | iou_gt(ey1, ex1, ey2, ex2, ea,
                         sel_y1[i], sel_x1[i], sel_y2[i], sel_x2[i], sel_ar[i]);
    }
    supp[tid] = sup ? 1u : 0u;
    __syncthreads();  // A: chunk boxes + supp visible
    // in-chunk suppression mask row (vs earlier candidates in this chunk)
    u64 r0 = 0, r1 = 0, r2 = 0, r3 = 0;
    const int jl = havec ? tid : 0;
    for (int t = 0; t < jl; ++t) {
      const bool kill = iou_gt(ey1, ex1, ey2, ex2, ea,
                               cy1[t], cx1[t], cy2[t], cx2[t], car[t]);
      const u64 m = kill ? 1ull : 0ull;
      if (t < 64) r0 |= m << t;
      else if (t < 128) r1 |= m << (t - 64);
      else if (t < 192) r2 |= m << (t - 128);
      else r3 |= m << (t - 192);
    }
    rows[tid * 4 + 0] = r0; rows[tid * 4 + 1] = r1;
    rows[tid * 4 + 2] = r2; rows[tid * 4 + 3] = r3;
    __syncthreads();  // B: rows visible
    // serial resolve (all threads redundantly; fully uniform -> no divergence)
    u64 a0 = 0, a1 = 0, a2 = 0, a3 = 0;
    int nc = cnt;
    int myslot = -1;
    for (int t = 0; t < lim; ++t) {
      bool ok = (supp[t] == 0u) && (nc < kKeep);
      if (ok) {
        const u64 hit = (rows[t * 4 + 0] & a0) | (rows[t * 4 + 1] & a1) |
                        (rows[t * 4 + 2] & a2) | (rows[t * 4 + 3] & a3);
        ok = (hit == 0ull);
      }
      if (ok) {
        if (t == tid) myslot = nc;
        if (t < 64) a0 |= 1ull << t;
        else if (t < 128) a1 |= 1ull << (t - 64);
        else if (t < 192) a2 |= 1ull << (t - 128);
        else a3 |= 1ull << (t - 192);
        ++nc;
      }
    }
    if (myslot >= 0) {
      sel_y1[myslot] = ey1; sel_x1[myslot] = ex1;
      sel_y2[myslot] = ey2; sel_x2[myslot] = ex2;
      sel_ar[myslot] = ea;
      out_s[myslot] = base_in[(size_t)eidx * kRow + 1 + c];  // exact score
      out_b[(size_t)myslot * 4 + 0] = ey1;
      out_b[(size_t)myslot * 4 + 1] = ex1;
      out_b[(size_t)myslot * 4 + 2] = ey2;
      out_b[(size_t)myslot * 4 + 3] = ex2;
    }
    cnt = nc;           // uniform across block
    basec += TPB;
    __syncthreads();    // C: sel visible; chunk scratch reusable
  }
  // empty slots
  for (int i = cnt + tid; i < kKeep; i += TPB) out_s[i] = -1.0f;
}

// One wave per batch: ws_s[task] is already sorted (score desc, idx asc) by
// construction (greedy NMS emits selections in that order), so top-200 is a
// 20-way merge of sorted lists. Lane l < 20 owns list l; 200 rounds of
// butterfly argmax over (score desc, flat-idx asc) == jax.lax.top_k order.
__global__ __launch_bounds__(64) void topk_kernel(const float* __restrict__ ws_s,
                                                  const float* __restrict__ ws_b,
                                                  float* __restrict__ out) {
  const int b = blockIdx.x;
  const int lane = threadIdx.x;
  const float* __restrict__ ss = ws_s + (size_t)b * kFlat;
  const float* __restrict__ bb = ws_b + (size_t)b * kFlat * 4;
  float* __restrict__ ob = out + (size_t)b * kTot * 6;

  __shared__ float ls[kFlat];  // [c][slot] == flat order, 24 KB

  for (int i = lane; i < kFlat; i += 64) ls[i] = ss[i];
  __syncthreads();

  int ptr = 0;
  float head = -2.0f;
  u32 hf = 0xFFFFFFFFu;
  if (lane < kC) { head = ls[lane * kKeep]; hf = (u32)(lane * kKeep); }

  int r = 0;
  for (; r < kTot; ++r) {
    float bs = head;
    u32 bf = hf;
#pragma unroll
    for (int off = 32; off; off >>= 1) {
      const float os = __shfl_xor(bs, off);
      const u32 of = __shfl_xor(bf, off);
      const bool take = pgt(os, of, bs, bf);
      bs = take ? os : bs;
      bf = take ? of : bf;
    }
    if (bs <= 0.0f) break;  // uniform: only empty (-1) heads remain
    if (hf == bf) {         // unique winner lane
      ob[r * 6 + 0] = (float)(lane + 1);  // class id = list id + 1
      ob[r * 6 + 1] = bs;
      ob[r * 6 + 2] = fminf(fmaxf(bb[(size_t)bf * 4 + 0], 0.0f), 1.0f);
      ob[r * 6 + 3] = fminf(fmaxf(bb[(size_t)bf * 4 + 1], 0.0f), 1.0f);
      ob[r * 6 + 4] = fminf(fmaxf(bb[(size_t)bf * 4 + 2], 0.0f), 1.0f);
      ob[r * 6 + 5] = fminf(fmaxf(bb[(size_t)bf * 4 + 3], 0.0f), 1.0f);
      ++ptr;
      if (ptr < kKeep) {
        head = ls[lane * kKeep + ptr];
        hf = (u32)(lane * kKeep + ptr);
      } else {
        head = -2.0f;
        hf = 0xFFFFFFFFu;
      }
    }
  }
  // invalid rows: class = 0+1 = 1, score 0, boxes 0
  for (int idx = r * 6 + lane; idx < kTot * 6; idx += 64) {
    ob[idx] = ((idx % 6) == 0) ? 1.0f : 0.0f;
  }
}

extern "C" void kernel_launch(void* const* d_in, const int* in_sizes, int n_in,
                              void* d_out, int out_size, void* d_ws, size_t ws_size,
                              hipStream_t stream) {
  const float* in = (const float*)d_in[0];
  float* out = (float*)d_out;
  float* ws_s = (float*)d_ws;                    // 320*300 floats
  float* ws_b = ws_s + (size_t)kB * kC * kKeep;  // 320*300*4 floats
  nms_kernel<<<dim3(kB * kC), dim3(TPB), 0, stream>>>(in, ws_s, ws_b);
  topk_kernel<<<dim3(kB), dim3(64), 0, stream>>>(ws_s, ws_b, out);
}

// Round 7
// 480.719 us; speedup vs baseline: 4.3935x; 1.0024x over previous
//
#include <hip/hip_runtime.h>

typedef unsigned long long u64;
typedef unsigned int u32;

namespace {
constexpr int kB = 16;
constexpr int kN = 8732;
constexpr int kC = 20;
constexpr int kRow = 25;      // 1 + C + 4
constexpr int kKeep = 300;    // NNS_K
constexpr int kTot = 200;     // K_TOTAL
constexpr float kConf = 0.01f;
// fl32(inter/union) > 0.45f  <=>  inter/union > 0.45f + ulp/2 (0.45f mantissa even,
// tie rounds down). kThr = 30198989 * 2^-26 exactly; 26-bit x 24-bit product
// is <= 50 bits -> exact in f64, so the f64 compare is an exact emulation.
constexpr double kThr = 0.45000000298023223876953125;

constexpr int TPB = 256;
constexpr int NBKT = 4096;         // score-bit buckets (bits>>14), range fits 3442
constexpr int kFlat = kC * kKeep;  // 6000
}

// exact emulation of reference: (union>0) && fl32(inter/union) > 0.45f
// (union >= 0 provable by rounding monotonicity; union==0 => inter==0 => false)
__device__ __forceinline__ bool iou_gt(float ay1, float ax1, float ay2, float ax2, float aa,
                                       float by1, float bx1, float by2, float bx2, float ba) {
  const float ty1 = fmaxf(ay1, by1);
  const float tx1 = fmaxf(ax1, bx1);
  const float ty2 = fminf(ay2, by2);
  const float tx2 = fminf(ax2, bx2);
  const float dy = fmaxf(__fsub_rn(ty2, ty1), 0.0f);
  const float dx = fmaxf(__fsub_rn(tx2, tx1), 0.0f);
  const float inter = __fmul_rn(dy, dx);
  const float uni = __fsub_rn(__fadd_rn(aa, ba), inter);
  return ((double)inter > kThr * (double)uni);
}

// bucket by high bits of score: monotone DESC (bucket 0 = highest scores).
// valid for s in (0.01, 1.0]: bits>>14 in [61583, 65024] -> bkt in [0, 3441].
__device__ __forceinline__ int bkt_of(float s) {
  return 65024 - (int)(__float_as_uint(s) >> 14);
}

// packed in-bucket sort key: same bucket => scores share bits[31:14], so
// (low14 desc, 16383-idx desc) == (score desc, idx asc). idx recoverable.
__device__ __forceinline__ u32 key_of(float s, int idx) {
  return ((__float_as_uint(s) & 0x3FFFu) << 14) | (u32)(16383 - idx);
}

// (score, flat-idx) strict ordering: higher score wins; ties -> lower idx.
__device__ __forceinline__ bool pgt(float as, u32 ai, float bs, u32 bi) {
  return (as > bs) || ((as == bs) && (ai < bi));
}

// exclusive prefix sum over hist[NBKT]; each of 256 threads owns 16 buckets.
// returns total count. hist[i] becomes the exclusive start of bucket i.
__device__ int excl_scan_hist(u32* hist, u32* wsum, int tid) {
  const int base = tid * 16;
  u32 loc[16];
  u32 s = 0;
#pragma unroll
  for (int i = 0; i < 16; ++i) { loc[i] = hist[base + i]; s += loc[i]; }
  int v = (int)s;
  const int lane = tid & 63;
#pragma unroll
  for (int off = 1; off < 64; off <<= 1) {
    const int u = __shfl_up(v, off);
    if (lane >= off) v += u;
  }
  if (lane == 63) wsum[tid >> 6] = (u32)v;
  __syncthreads();
  u32 woff = 0, total = 0;
#pragma unroll
  for (int w = 0; w < TPB / 64; ++w) {
    const u32 t = wsum[w];
    total += t;
    if (w < (tid >> 6)) woff += t;
  }
  u32 run = woff + (u32)v - s;
#pragma unroll
  for (int i = 0; i < 16; ++i) { hist[base + i] = run; run += loc[i]; }
  __syncthreads();
  return (int)total;
}

// Transpose pass: scores_t[b][c][n] (coalesced per-class columns) + box SoA.
// Tile of 256 rows staged in LDS (stride-25 word reads are conflict-free).
__global__ __launch_bounds__(TPB) void prep_kernel(const float* __restrict__ in,
                                                   float* __restrict__ st,
                                                   float* __restrict__ py1,
                                                   float* __restrict__ px1,
                                                   float* __restrict__ py2,
                                                   float* __restrict__ px2) {
  const int b = blockIdx.y;
  const int n0 = blockIdx.x * TPB;
  const int tid = threadIdx.x;
  const int rows = min(TPB, kN - n0);

  __shared__ float tile[TPB * kRow];
  const float* __restrict__ src = in + ((size_t)b * kN + n0) * kRow;
  const int total = rows * kRow;
  for (int i = tid; i < total; i += TPB) tile[i] = src[i];
  __syncthreads();
  if (tid < rows) {
    const int n = n0 + tid;
    const float* row = &tile[tid * kRow];
#pragma unroll
    for (int c = 0; c < kC; ++c)
      st[((size_t)b * kC + c) * kN + n] = row[1 + c];
    py1[(size_t)b * kN + n] = row[21];
    px1[(size_t)b * kN + n] = row[22];
    py2[(size_t)b * kN + n] = row[23];
    px2[(size_t)b * kN + n] = row[24];
  }
}

// One block per (b,c) task. Phase 1: exact stable sort of candidates by
// (score desc, idx asc) via bucket sort. Phase 2: chunked sequential greedy
// NMS scan over the sorted order (exact reference semantics incl. cnt<300).
// X=true: read transposed scores + box SoA (coalesced). X=false: strided
// fallback straight from the input (used if ws_size is too small).
template <bool X>
__global__ __launch_bounds__(TPB) void nms_kernel(const float* __restrict__ in,
                                                  const float* __restrict__ st,
                                                  const float* __restrict__ py1,
                                                  const float* __restrict__ px1,
                                                  const float* __restrict__ py2,
                                                  const float* __restrict__ px2,
                                                  float* __restrict__ ws_s,
                                                  float* __restrict__ ws_b) {
  const int task = blockIdx.x;
  const int b = task / kC;
  const int c = task - b * kC;
  const int tid = threadIdx.x;
  const float* __restrict__ base_in = in + (size_t)b * kN * kRow;
  const float* __restrict__ stc = st + ((size_t)b * kC + c) * kN;
  const size_t bo = (size_t)b * kN;

  __shared__ __align__(16) unsigned char ovl[16384];  // hist | phase-2 scratch
  __shared__ u32 skey[kN];                            // sorted packed keys
  __shared__ float sel_y1[kKeep], sel_x1[kKeep], sel_y2[kKeep], sel_x2[kKeep],
      sel_ar[kKeep];
  __shared__ u32 wsum[TPB / 64];

  u32* hist = (u32*)ovl;
  for (int i = tid; i < NBKT; i += TPB) hist[i] = 0;
  __syncthreads();
  // histogram pass (coalesced when X)
  for (int k = 0; k < (kN + TPB - 1) / TPB; ++k) {
    const int n = tid + k * TPB;
    if (n < kN) {
      const float s = X ? stc[n] : base_in[(size_t)n * kRow + 1 + c];
      if (s > kConf) atomicAdd(&hist[bkt_of(s)], 1u);
    }
  }
  __syncthreads();
  const int ncand = excl_scan_hist(hist, wsum, tid);
  // scatter pass (atomic order nondeterministic; fixed by in-bucket sort)
  for (int k = 0; k < (kN + TPB - 1) / TPB; ++k) {
    const int n = tid + k * TPB;
    if (n < kN) {
      const float s = X ? stc[n] : base_in[(size_t)n * kRow + 1 + c];
      if (s > kConf) {
        const u32 pos = atomicAdd(&hist[bkt_of(s)], 1u);
        skey[pos] = key_of(s, n);
      }
    }
  }
  __syncthreads();
  // in-bucket insertion sort, descending u32 key (exact total order)
  for (int bkt = tid; bkt < NBKT; bkt += TPB) {
    const int s0 = (bkt == 0) ? 0 : (int)hist[bkt - 1];  // post-scatter = ends
    const int e0 = (int)hist[bkt];
    for (int i = s0 + 1; i < e0; ++i) {
      const u32 kk = skey[i];
      int j = i - 1;
      while (j >= s0 && kk > skey[j]) { skey[j + 1] = skey[j]; --j; }
      skey[j + 1] = kk;
    }
  }
  __syncthreads();  // hist dead -> overlay becomes phase-2 scratch

  u64* rows = (u64*)ovl;               // [256][4] = 8192 B
  float* cy1 = (float*)(ovl + 8192);   // chunk boxes, 1 KB each
  float* cx1 = (float*)(ovl + 9216);
  float* cy2 = (float*)(ovl + 10240);
  float* cx2 = (float*)(ovl + 11264);
  float* car = (float*)(ovl + 12288);
  u32* supp = (u32*)(ovl + 13312);     // 1 KB (total 14336 <= 16384)

  float* __restrict__ out_s = ws_s + (size_t)task * kKeep;
  float* __restrict__ out_b = ws_b + (size_t)task * kKeep * 4;

  int cnt = 0;
  int basec = 0;
  while (cnt < kKeep && basec < ncand) {
    const int rank = basec + tid;
    const bool havec = rank < ncand;
    const int lim = min(TPB, ncand - basec);
    float ey1 = 0, ex1 = 0, ey2 = 0, ex2 = 0, ea = 0;
    int eidx = 0;
    if (havec) {
      eidx = 16383 - (int)(skey[rank] & 0x3FFFu);
      if (X) {
        ey1 = py1[bo + eidx]; ex1 = px1[bo + eidx];
        ey2 = py2[bo + eidx]; ex2 = px2[bo + eidx];
      } else {
        const float* r = base_in + (size_t)eidx * kRow;
        ey1 = r[21]; ex1 = r[22]; ey2 = r[23]; ex2 = r[24];
      }
      ea = __fmul_rn(__fsub_rn(ey2, ey1), __fsub_rn(ex2, ex1));
    }
    cy1[tid] = ey1; cx1[tid] = ex1; cy2[tid] = ey2; cx2[tid] = ex2; car[tid] = ea;
    // test vs already-selected set (LDS broadcast reads)
    bool sup = !havec;
    for (int i = 0; i < cnt; ++i) {
      sup = sup | iou_gt(ey1, ex1, ey2, ex2, ea,
                         sel_y1[i], sel_x1[i], sel_y2[i], sel_x2[i], sel_ar[i]);
    }
    supp[tid] = sup ? 1u : 0u;
    __syncthreads();  // A: chunk boxes + supp visible
    // in-chunk suppression mask row (vs earlier candidates in this chunk)
    u64 r0 = 0, r1 = 0, r2 = 0, r3 = 0;
    const int jl = havec ? tid : 0;
    for (int t = 0; t < jl; ++t) {
      const bool kill = iou_gt(ey1, ex1, ey2, ex2, ea,
                               cy1[t], cx1[t], cy2[t], cx2[t], car[t]);
      const u64 m = kill ? 1ull : 0ull;
      if (t < 64) r0 |= m << t;
      else if (t < 128) r1 |= m << (t - 64);
      else if (t < 192) r2 |= m << (t - 128);
      else r3 |= m << (t - 192);
    }
    rows[tid * 4 + 0] = r0; rows[tid * 4 + 1] = r1;
    rows[tid * 4 + 2] = r2; rows[tid * 4 + 3] = r3;
    __syncthreads();  // B: rows visible
    // serial resolve (all threads redundantly; fully uniform -> no divergence)
    u64 a0 = 0, a1 = 0, a2 = 0, a3 = 0;
    int nc = cnt;
    int myslot = -1;
    for (int t = 0; t < lim; ++t) {
      bool ok = (supp[t] == 0u) && (nc < kKeep);
      if (ok) {
        const u64 hit = (rows[t * 4 + 0] & a0) | (rows[t * 4 + 1] & a1) |
                        (rows[t * 4 + 2] & a2) | (rows[t * 4 + 3] & a3);
        ok = (hit == 0ull);
      }
      if (ok) {
        if (t == tid) myslot = nc;
        if (t < 64) a0 |= 1ull << t;
        else if (t < 128) a1 |= 1ull << (t - 64);
        else if (t < 192) a2 |= 1ull << (t - 128);
        else a3 |= 1ull << (t - 192);
        ++nc;
      }
    }
    if (myslot >= 0) {
      sel_y1[myslot] = ey1; sel_x1[myslot] = ex1;
      sel_y2[myslot] = ey2; sel_x2[myslot] = ex2;
      sel_ar[myslot] = ea;
      out_s[myslot] = X ? stc[eidx] : base_in[(size_t)eidx * kRow + 1 + c];
      out_b[(size_t)myslot * 4 + 0] = ey1;
      out_b[(size_t)myslot * 4 + 1] = ex1;
      out_b[(size_t)myslot * 4 + 2] = ey2;
      out_b[(size_t)myslot * 4 + 3] = ex2;
    }
    cnt = nc;           // uniform across block
    basec += TPB;
    __syncthreads();    // C: sel visible; chunk scratch reusable
  }
  // empty slots
  for (int i = cnt + tid; i < kKeep; i += TPB) out_s[i] = -1.0f;
}

// One wave per batch: ws_s[task] is already sorted (score desc, idx asc) by
// construction, so top-200 is a 20-way merge of sorted lists. Lane l < 20
// owns list l. head+hnext and their boxes are prefetched into registers so
// each round's critical path is just the butterfly reduce (no memory wait).
__global__ __launch_bounds__(64) void topk_kernel(const float* __restrict__ ws_s,
                                                  const float* __restrict__ ws_b,
                                                  float* __restrict__ out) {
  const int b = blockIdx.x;
  const int lane = threadIdx.x;
  const float* __restrict__ ss = ws_s + (size_t)b * kFlat;
  const float* __restrict__ bb = ws_b + (size_t)b * kFlat * 4;
  float* __restrict__ ob = out + (size_t)b * kTot * 6;

  __shared__ float ls[kFlat];  // [c][slot] == flat order, 24 KB

  for (int i = lane; i < kFlat; i += 64) ls[i] = ss[i];
  __syncthreads();

  int ptr = 0;
  float head = -2.0f, hnext = -2.0f;
  u32 hf = 0xFFFFFFFFu;
  float q0 = 0, q1 = 0, q2 = 0, q3 = 0;      // head's box
  float p0 = 0, p1 = 0, p2 = 0, p3 = 0;      // hnext's box
  if (lane < kC) {
    const u32 f0 = (u32)(lane * kKeep);
    head = ls[f0];
    hf = f0;
    hnext = ls[f0 + 1];
    q0 = bb[(size_t)f0 * 4 + 0]; q1 = bb[(size_t)f0 * 4 + 1];
    q2 = bb[(size_t)f0 * 4 + 2]; q3 = bb[(size_t)f0 * 4 + 3];
    p0 = bb[(size_t)(f0 + 1) * 4 + 0]; p1 = bb[(size_t)(f0 + 1) * 4 + 1];
    p2 = bb[(size_t)(f0 + 1) * 4 + 2]; p3 = bb[(size_t)(f0 + 1) * 4 + 3];
  }

  int r = 0;
  for (; r < kTot; ++r) {
    float bs = head;
    u32 bf = hf;
#pragma unroll
    for (int off = 32; off; off >>= 1) {
      const float os = __shfl_xor(bs, off);
      const u32 of = __shfl_xor(bf, off);
      const bool take = pgt(os, of, bs, bf);
      bs = take ? os : bs;
      bf = take ? of : bf;
    }
    if (bs <= 0.0f) break;  // uniform: only empty (-1) heads remain
    if (hf == bf) {         // unique winner lane; everything needed is in regs
      ob[r * 6 + 0] = (float)(lane + 1);  // class id = list id + 1
      ob[r * 6 + 1] = bs;
      ob[r * 6 + 2] = fminf(fmaxf(q0, 0.0f), 1.0f);
      ob[r * 6 + 3] = fminf(fmaxf(q1, 0.0f), 1.0f);
      ob[r * 6 + 4] = fminf(fmaxf(q2, 0.0f), 1.0f);
      ob[r * 6 + 5] = fminf(fmaxf(q3, 0.0f), 1.0f);
      ++ptr;
      head = hnext;                        // ready in regs: no LDS wait
      hf = (u32)(lane * kKeep + ptr);
      q0 = p0; q1 = p1; q2 = p2; q3 = p3;
      const int nx = ptr + 1;
      if (nx < kKeep) {                    // issue prefetch; used >=1 round later
        const u32 fn = (u32)(lane * kKeep + nx);
        hnext = ls[fn];
        p0 = bb[(size_t)fn * 4 + 0]; p1 = bb[(size_t)fn * 4 + 1];
        p2 = bb[(size_t)fn * 4 + 2]; p3 = bb[(size_t)fn * 4 + 3];
      } else {
        hnext = -2.0f;
      }
    }
  }
  // invalid rows: class = 0+1 = 1, score 0, boxes 0
  for (int idx = r * 6 + lane; idx < kTot * 6; idx += 64) {
    ob[idx] = ((idx % 6) == 0) ? 1.0f : 0.0f;
  }
}

extern "C" void kernel_launch(void* const* d_in, const int* in_sizes, int n_in,
                              void* d_out, int out_size, void* d_ws, size_t ws_size,
                              hipStream_t stream) {
  const float* in = (const float*)d_in[0];
  float* out = (float*)d_out;
  float* ws_s = (float*)d_ws;                    // 96000 floats
  float* ws_b = ws_s + (size_t)kB * kC * kKeep;  // 384000 floats
  float* st = ws_b + (size_t)kB * kC * kKeep * 4;          // 2,794,240 floats
  float* py1 = st + (size_t)kB * kC * kN;                  // 139,712 each
  float* px1 = py1 + (size_t)kB * kN;
  float* py2 = px1 + (size_t)kB * kN;
  float* px2 = py2 + (size_t)kB * kN;
  const size_t needed =
      ((size_t)kB * kC * kKeep * 5 + (size_t)kB * kC * kN + (size_t)kB * kN * 4) *
      sizeof(float);
  if (ws_size >= needed) {
    prep_kernel<<<dim3((kN + TPB - 1) / TPB, kB), dim3(TPB), 0, stream>>>(
        in, st, py1, px1, py2, px2);
    nms_kernel<true><<<dim3(kB * kC), dim3(TPB), 0, stream>>>(
        in, st, py1, px1, py2, px2, ws_s, ws_b);
  } else {
    nms_kernel<false><<<dim3(kB * kC), dim3(TPB), 0, stream>>>(
        in, nullptr, nullptr, nullptr, nullptr, nullptr, ws_s, ws_b);
  }
  topk_kernel<<<dim3(kB), dim3(64), 0, stream>>>(ws_s, ws_b, out);
}